// Round 6
// baseline (132.550 us; speedup 1.0000x reference)
//
#include <hip/hip_runtime.h>

typedef int   i32x8v __attribute__((ext_vector_type(8)));
typedef float f32x16 __attribute__((ext_vector_type(16)));

#define GLOBAL_AS(p) ((const __attribute__((address_space(1))) void*)(p))
#define LDS_AS(p)    ((__attribute__((address_space(3))) void*)(p))
#define BAR()     __builtin_amdgcn_s_barrier()
#define VMCNT(n)  asm volatile("s_waitcnt vmcnt(" #n ")" ::: "memory")
#define SP1       __builtin_amdgcn_s_setprio(1);
#define SP0       __builtin_amdgcn_s_setprio(0);

// ---------------- exp(x) -> fp8 e4m3, contiguous [M][K] ----------------
__global__ void expcvt_a8_kernel(const float* __restrict__ x,
                                 unsigned* __restrict__ y, size_t n8) {
  size_t tid0   = (size_t)blockIdx.x * blockDim.x + threadIdx.x;
  size_t stride = (size_t)gridDim.x * blockDim.x;
  const float4* x4 = (const float4*)x;
  for (size_t i = tid0; i < n8; i += stride) {
    float4 v0 = x4[2 * i], v1 = x4[2 * i + 1];
    int lo = 0, hi = 0;
    lo = __builtin_amdgcn_cvt_pk_fp8_f32(__expf(v0.x), __expf(v0.y), lo, false);
    lo = __builtin_amdgcn_cvt_pk_fp8_f32(__expf(v0.z), __expf(v0.w), lo, true);
    hi = __builtin_amdgcn_cvt_pk_fp8_f32(__expf(v1.x), __expf(v1.y), hi, false);
    hi = __builtin_amdgcn_cvt_pk_fp8_f32(__expf(v1.z), __expf(v1.w), hi, true);
    ((uint2*)y)[i] = make_uint2((unsigned)lo, (unsigned)hi);
  }
}

// ------------- exp(w) -> fp8 e4m3, transposed: Bt[n][d] -------------
__global__ void expcvt_wt8_kernel(const float* __restrict__ w,
                                  unsigned char* __restrict__ bt,
                                  int D, int O) {
  __shared__ unsigned char tile[32][33];
  int c0 = blockIdx.x * 32;   // O (col of w)
  int r0 = blockIdx.y * 32;   // D (row of w)
  int tx = threadIdx.x;       // 0..31
  int ty = threadIdx.y;       // 0..7
#pragma unroll
  for (int j = 0; j < 4; ++j) {
    int r = r0 + ty + j * 8;
    float e = __expf(w[(size_t)r * O + c0 + tx]);
    int p = __builtin_amdgcn_cvt_pk_fp8_f32(e, e, 0, false);
    tile[ty + j * 8][tx] = (unsigned char)(p & 0xFF);
  }
  __syncthreads();
  int t    = ty * 32 + tx;     // 0..255
  int orow = t >> 3;           // 0..31  (O index within tile)
  int b4   = (t & 7) * 4;      // 4-byte group along D
  unsigned u = (unsigned)tile[b4][orow] | ((unsigned)tile[b4 + 1][orow] << 8) |
               ((unsigned)tile[b4 + 2][orow] << 16) |
               ((unsigned)tile[b4 + 3][orow] << 24);
  *(unsigned*)(bt + (size_t)(c0 + orow) * D + r0 + b4) = u;
}

// ------------- 256x256 8-phase MX-fp8 MFMA GEMM, log+bias epilogue -------------
// A  : [M][K] fp8 (exp_inputs)    Bt : [N][K] fp8 (exp_w transposed)
// out: [M][N] f32 = log(A@B) + bias[n]
// 512 thr = 8 waves (2 Mrow x 4 Ncol), per-wave C 128x64 = 4mb x 2nb of 32x32.
// LDS 128 KiB, slot s = tile&1: A at s*65536 (2x 16KB halves of [128][128B]),
// B at +32768. Swizzle at 32B granularity: physical col = col ^ ((row&3)<<5)
// (involution; applied on pre-swizzled global_load_lds source AND on reads).
// Fragments are 32B-contiguous -> one i32x8 LDS load = 2 adjacent ds_read_b128
// (no cross-register packing). 16B sub-reads are 2-way quad-aliased = free.

#define LOAD_A(PTR, MH)                                                     \
  aF[0][0] = *(const i32x8v*)((PTR) + ((MH)*2 + 0) * 4096 + c0);            \
  aF[0][1] = *(const i32x8v*)((PTR) + ((MH)*2 + 0) * 4096 + c1);            \
  aF[1][0] = *(const i32x8v*)((PTR) + ((MH)*2 + 1) * 4096 + c0);            \
  aF[1][1] = *(const i32x8v*)((PTR) + ((MH)*2 + 1) * 4096 + c1);

#define LOAD_B(DST, PTR, NB)                                                \
  DST[0] = *(const i32x8v*)((PTR) + (NB)*4096 + c0);                        \
  DST[1] = *(const i32x8v*)((PTR) + (NB)*4096 + c1);

#define MFMA_Q(MH, NB, BF)                                                  \
  _Pragma("unroll") for (int mm = 0; mm < 2; ++mm)                          \
  _Pragma("unroll") for (int ks = 0; ks < 2; ++ks)                          \
    acc[(MH)*2 + mm][NB] = __builtin_amdgcn_mfma_scale_f32_32x32x64_f8f6f4( \
        aF[mm][ks], BF[ks], acc[(MH)*2 + mm][NB], 0, 0,                     \
        0, 0x7F7F7F7F, 0, 0x7F7F7F7F);

__global__ __launch_bounds__(512, 2) void gemm8mx_log_kernel(
    const unsigned char* __restrict__ A, const unsigned char* __restrict__ Bt,
    const float* __restrict__ bias, float* __restrict__ out,
    int M, int N, int K) {
  __shared__ char lds[131072];

  const int tid  = threadIdx.x;
  const int wid  = tid >> 6, lane = tid & 63;
  const int wr   = wid >> 2, wc = wid & 3;
  const int l31  = lane & 31, lk = lane >> 5;
  const int NT   = K >> 7;        // 128B K-tiles (16)
  const int NIT  = NT >> 1;       // iterations (8)
  const size_t Kb = (size_t)K;    // bytes per row (fp8)

  // XCD-aware bijective swizzle (gridDim.x % 8 == 0 here: 512)
  const int cpx = gridDim.x >> 3;
  const int v   = (blockIdx.x & 7) * cpx + (blockIdx.x >> 3);
  const int nbn = N >> 8;
  const int bm  = v / nbn, bn = v % nbn;
  const int brow = bm << 8, bcol = bn << 8;

  // 32B-granular swizzled fragment offsets: logical = ks*64 + lk*32,
  // physical = logical ^ ((row&3)<<5); row&3 == l31&3 for all mb/nb.
  const int swz = (l31 & 3) << 5;
  const int c0  = (lk * 32) ^ swz;     // ks = 0
  const int c1  = c0 ^ 64;             // ks = 1

  const char* pA0 = lds + wr * 16384 + l31 * 128;
  const char* pA1 = pA0 + 65536;
  const char* pB0 = lds + 32768 + (wc >> 1) * 16384 + ((wc & 1) * 64 + l31) * 128;
  const char* pB1 = pB0 + 65536;

  // stage one 16KB half-tile (2 x global_load_lds of 16B x 512 threads)
  auto STAGE = [&](int t, int isB, int h) {
    const int tt = (t < NT) ? t : NT - 1;     // clamp keeps vmcnt ledger uniform
    const char* src = isB ? (const char*)Bt : (const char*)A;
    const int g0 = (isB ? bcol : brow) + h * 128;
    char* base = lds + (t & 1) * 65536 + isB * 32768 + h * 16384;
#pragma unroll
    for (int i = 0; i < 2; ++i) {
      const int o    = i * 8192 + tid * 16;
      const int row  = o >> 7;
      const int colb = (o & 127) ^ ((row & 3) << 5);   // inverse-swizzled source
      const char* g  = src + (size_t)(g0 + row) * Kb + (size_t)tt * 128 + colb;
      char* dst = base + i * 8192 + (tid >> 6) * 1024;  // wave-uniform base
      __builtin_amdgcn_global_load_lds(GLOBAL_AS(g), LDS_AS(dst), 16, 0, 0);
    }
  };

  f32x16 acc[4][2];
#pragma unroll
  for (int m = 0; m < 4; ++m)
#pragma unroll
    for (int n = 0; n < 2; ++n) acc[m][n] = (f32x16)0.0f;

  i32x8v aF[2][2], bF0[2], bF1[2];

  // prologue: t0 fully + t1 {Ah0, Ah1, Bh0}  (7 half-tiles = 14 loads)
  STAGE(0, 1, 0); STAGE(0, 0, 0); STAGE(0, 0, 1); STAGE(0, 1, 1);
  STAGE(1, 0, 0); STAGE(1, 0, 1); STAGE(1, 1, 0);
  VMCNT(6);   // t0 resident; t1's 3 half-tiles stay in flight
  BAR();
  LOAD_A(pA0, 0)          // A mh0 (t0)
  LOAD_B(bF0, pB0, 0)     // B nb0 (t0)

  for (int j = 0; j < NIT; ++j) {
    const int t1 = 2 * j + 1, t2 = 2 * j + 2, t3 = 2 * j + 3;
    // -- P1: stage Bh1(t1)->s1; Q(mh0,nb0); rd bF1(s0)
    STAGE(t1, 1, 1);
    SP1 MFMA_Q(0, 0, bF0) SP0
    LOAD_B(bF1, pB0, 1)
    BAR();
    // -- P2: Q(mh0,nb1); rd A mh1 (aF dead after MFMA)
    SP1 MFMA_Q(0, 1, bF1) SP0
    LOAD_A(pA0, 1)
    BAR();
    // -- P3: Q(mh1,nb1)
    SP1 MFMA_Q(1, 1, bF1) SP0
    BAR();
    // -- P4: stage Bh0(t2)+Ah0(t2)->s0; vmcnt(4) -> t1 resident; barrier;
    //        Q(mh1,nb0); rd A mh0(s1) + bF0(s1)
    STAGE(t2, 1, 0); STAGE(t2, 0, 0);
    VMCNT(4);
    BAR();
    SP1 MFMA_Q(1, 0, bF0) SP0
    LOAD_A(pA1, 0)
    LOAD_B(bF0, pB1, 0)
    BAR();
    // -- P5: stage Ah1(t2); Q(mh0,nb0)'; rd bF1(s1)
    STAGE(t2, 0, 1);
    SP1 MFMA_Q(0, 0, bF0) SP0
    LOAD_B(bF1, pB1, 1)
    BAR();
    // -- P6: stage Bh1(t2); Q(mh0,nb1)'; rd A mh1(s1)
    STAGE(t2, 1, 1);
    SP1 MFMA_Q(0, 1, bF1) SP0
    LOAD_A(pA1, 1)
    BAR();
    // -- P7: Q(mh1,nb1)'
    SP1 MFMA_Q(1, 1, bF1) SP0
    BAR();
    // -- P8: stage Ah0+Ah1+Bh0(t3)->s1; vmcnt(6) -> t2 resident; barrier;
    //        Q(mh1,nb0)'; rd A mh0(next,s0) + bF0(next,s0)
    STAGE(t3, 0, 0); STAGE(t3, 0, 1); STAGE(t3, 1, 0);
    VMCNT(6);
    BAR();
    SP1 MFMA_Q(1, 0, bF0) SP0
    LOAD_A(pA0, 0)
    LOAD_B(bF0, pB0, 0)
    BAR();
  }

  VMCNT(0);

  // epilogue: out = log(acc) + bias, nontemporal (written once, never read;
  // keep L2/L3 for the A/B panels).
  // 32x32 C/D layout: col = lane&31, row = (reg&3) + 8*(reg>>2) + 4*(lane>>5)
  const int col0 = bcol + wc * 64 + l31;
  const int row0 = brow + wr * 128 + lk * 4;
  const float bv0 = bias[col0], bv1 = bias[col0 + 32];
#pragma unroll
  for (int mb = 0; mb < 4; ++mb) {
#pragma unroll
    for (int rg = 0; rg < 16; ++rg) {
      const int row = row0 + mb * 32 + (rg & 3) + 8 * (rg >> 2);
      const size_t ro = (size_t)row * N + col0;
      __builtin_nontemporal_store(__logf(acc[mb][0][rg]) + bv0, &out[ro]);
      __builtin_nontemporal_store(__logf(acc[mb][1][rg]) + bv1, &out[ro + 32]);
    }
  }
}

extern "C" void kernel_launch(void* const* d_in, const int* in_sizes, int n_in,
                              void* d_out, int out_size, void* d_ws, size_t ws_size,
                              hipStream_t stream) {
  const float* inputs = (const float*)d_in[0];
  const float* w      = (const float*)d_in[1];
  const float* bias   = (const float*)d_in[2];
  float* out = (float*)d_out;

  const int O = in_sizes[2];                 // 2048
  const int D = in_sizes[1] / O;             // 2048
  const size_t MD = (size_t)in_sizes[0];     // M*D
  const int M = (int)(MD / (size_t)D);       // 16384

  unsigned char* A8  = (unsigned char*)d_ws;
  unsigned char* Bt8 = (unsigned char*)d_ws + MD;

  expcvt_a8_kernel<<<2048, 256, 0, stream>>>(inputs, (unsigned*)A8, MD / 8);

  dim3 tg(O / 32, D / 32);
  expcvt_wt8_kernel<<<tg, dim3(32, 8), 0, stream>>>(w, Bt8, D, O);

  dim3 grid((M / 256) * (O / 256));
  gemm8mx_log_kernel<<<grid, 512, 0, stream>>>(A8, Bt8, bias, out, M, O, D);
}

// Round 7
// 110.554 us; speedup vs baseline: 1.1990x; 1.1990x over previous
//
#include <hip/hip_runtime.h>

typedef int   i32x4v __attribute__((ext_vector_type(4)));
typedef int   i32x8v __attribute__((ext_vector_type(8)));
typedef float f32x16 __attribute__((ext_vector_type(16)));

#define GLOBAL_AS(p) ((const __attribute__((address_space(1))) void*)(p))
#define LDS_AS(p)    ((__attribute__((address_space(3))) void*)(p))
#define BAR()     __builtin_amdgcn_s_barrier()
#define VMCNT(n)  asm volatile("s_waitcnt vmcnt(" #n ")" ::: "memory")
#define SP1       __builtin_amdgcn_s_setprio(1);
#define SP0       __builtin_amdgcn_s_setprio(0);

// ---------------- exp(x) -> fp8 e4m3, contiguous [M][K] ----------------
__global__ void expcvt_a8_kernel(const float* __restrict__ x,
                                 unsigned* __restrict__ y, size_t n8) {
  size_t tid0   = (size_t)blockIdx.x * blockDim.x + threadIdx.x;
  size_t stride = (size_t)gridDim.x * blockDim.x;
  const float4* x4 = (const float4*)x;
  for (size_t i = tid0; i < n8; i += stride) {
    float4 v0 = x4[2 * i], v1 = x4[2 * i + 1];
    int lo = 0, hi = 0;
    lo = __builtin_amdgcn_cvt_pk_fp8_f32(__expf(v0.x), __expf(v0.y), lo, false);
    lo = __builtin_amdgcn_cvt_pk_fp8_f32(__expf(v0.z), __expf(v0.w), lo, true);
    hi = __builtin_amdgcn_cvt_pk_fp8_f32(__expf(v1.x), __expf(v1.y), hi, false);
    hi = __builtin_amdgcn_cvt_pk_fp8_f32(__expf(v1.z), __expf(v1.w), hi, true);
    ((uint2*)y)[i] = make_uint2((unsigned)lo, (unsigned)hi);
  }
}

// ------------- exp(w) -> fp8 e4m3, transposed: Bt[n][d] -------------
__global__ void expcvt_wt8_kernel(const float* __restrict__ w,
                                  unsigned char* __restrict__ bt,
                                  int D, int O) {
  __shared__ unsigned char tile[32][33];
  int c0 = blockIdx.x * 32;   // O (col of w)
  int r0 = blockIdx.y * 32;   // D (row of w)
  int tx = threadIdx.x;       // 0..31
  int ty = threadIdx.y;       // 0..7
#pragma unroll
  for (int j = 0; j < 4; ++j) {
    int r = r0 + ty + j * 8;
    float e = __expf(w[(size_t)r * O + c0 + tx]);
    int p = __builtin_amdgcn_cvt_pk_fp8_f32(e, e, 0, false);
    tile[ty + j * 8][tx] = (unsigned char)(p & 0xFF);
  }
  __syncthreads();
  int t    = ty * 32 + tx;     // 0..255
  int orow = t >> 3;           // 0..31  (O index within tile)
  int b4   = (t & 7) * 4;      // 4-byte group along D
  unsigned u = (unsigned)tile[b4][orow] | ((unsigned)tile[b4 + 1][orow] << 8) |
               ((unsigned)tile[b4 + 2][orow] << 16) |
               ((unsigned)tile[b4 + 3][orow] << 24);
  *(unsigned*)(bt + (size_t)(c0 + orow) * D + r0 + b4) = u;
}

// ------------- 256x256 8-phase MX-fp8 MFMA GEMM, log+bias epilogue -------------
// A  : [M][K] fp8 (exp_inputs)    Bt : [N][K] fp8 (exp_w transposed)
// out: [M][N] f32 = log(A@B) + bias[n]
// 512 thr = 8 waves (2 Mrow x 4 Ncol), per-wave C 128x64 = 4mb x 2nb of 32x32.
// LDS 128 KiB, slot s = tile&1: A at s*65536 (2x 16KB halves of [128][128B]),
// B at +32768.
// Swizzle sigma'(row) = ((row&7)<<4) ^ ((row&16)<<2): 16B-granular involution,
// distinct slots within BOTH contiguous-8 lane groups (row bits 0-2) AND
// quad-interleaved groups {l,l+16,l+32,l+48} (row bit4 + lk bit). Applied on
// pre-swizzled global_load_lds source AND on ds_read addresses.
// Fragment = two b128 at c00 / c00^16 (shufflevector-paired into one i32x8).

#define FR(P, C0, C1)                                                       \
  __builtin_shufflevector(*(const i32x4v*)((P) + (C0)),                     \
                          *(const i32x4v*)((P) + (C1)), 0, 1, 2, 3, 4, 5, 6, 7)

#define LOAD_A(PTR, MH)                                                     \
  aF[0][0] = FR((PTR) + ((MH)*2 + 0) * 4096, c00, c01);                     \
  aF[0][1] = FR((PTR) + ((MH)*2 + 0) * 4096, c10, c11);                     \
  aF[1][0] = FR((PTR) + ((MH)*2 + 1) * 4096, c00, c01);                     \
  aF[1][1] = FR((PTR) + ((MH)*2 + 1) * 4096, c10, c11);

#define LOAD_B(DST, PTR, NB)                                                \
  DST[0] = FR((PTR) + (NB)*4096, c00, c01);                                 \
  DST[1] = FR((PTR) + (NB)*4096, c10, c11);

#define MFMA_Q(MH, NB, BF)                                                  \
  _Pragma("unroll") for (int mm = 0; mm < 2; ++mm)                          \
  _Pragma("unroll") for (int ks = 0; ks < 2; ++ks)                          \
    acc[(MH)*2 + mm][NB] = __builtin_amdgcn_mfma_scale_f32_32x32x64_f8f6f4( \
        aF[mm][ks], BF[ks], acc[(MH)*2 + mm][NB], 0, 0,                     \
        0, 0x7F7F7F7F, 0, 0x7F7F7F7F);

__global__ __launch_bounds__(512, 2) void gemm8mx_log_kernel(
    const unsigned char* __restrict__ A, const unsigned char* __restrict__ Bt,
    const float* __restrict__ bias, float* __restrict__ out,
    int M, int N, int K) {
  __shared__ char lds[131072];

  const int tid  = threadIdx.x;
  const int wid  = tid >> 6, lane = tid & 63;
  const int wr   = wid >> 2, wc = wid & 3;
  const int l31  = lane & 31, lk = lane >> 5;
  const int NT   = K >> 7;        // 128B K-tiles (16)
  const int NIT  = NT >> 1;       // iterations (8)
  const size_t Kb = (size_t)K;    // bytes per row (fp8)

  // XCD-aware bijective swizzle (gridDim.x % 8 == 0 here: 512)
  const int cpx = gridDim.x >> 3;
  const int v   = (blockIdx.x & 7) * cpx + (blockIdx.x >> 3);
  const int nbn = N >> 8;
  const int bm  = v / nbn, bn = v % nbn;
  const int brow = bm << 8, bcol = bn << 8;

  // sigma'(l31) = ((l31&7)<<4) ^ ((l31&16)<<2); fragment offsets:
  // c(sub,lk,ks) = (ks*64 + lk*32 + sub*16) ^ sigma'  (XOR identities hold:
  // sigma' only touches bits 4 and 6; bases are multiples of 16)
  const int swz = ((l31 & 7) << 4) ^ ((l31 & 16) << 2);
  const int c00 = (lk * 32) ^ swz;
  const int c01 = c00 ^ 16;
  const int c10 = c00 ^ 64;
  const int c11 = c00 ^ 80;

  const char* pA0 = lds + wr * 16384 + l31 * 128;
  const char* pA1 = pA0 + 65536;
  const char* pB0 = lds + 32768 + (wc >> 1) * 16384 + ((wc & 1) * 64 + l31) * 128;
  const char* pB1 = pB0 + 65536;

  // stage one 16KB half-tile (2 x global_load_lds of 16B x 512 threads)
  auto STAGE = [&](int t, int isB, int h) {
    const int tt = (t < NT) ? t : NT - 1;     // clamp keeps vmcnt ledger uniform
    const char* src = isB ? (const char*)Bt : (const char*)A;
    const int g0 = (isB ? bcol : brow) + h * 128;
    char* base = lds + (t & 1) * 65536 + isB * 32768 + h * 16384;
#pragma unroll
    for (int i = 0; i < 2; ++i) {
      const int o    = i * 8192 + tid * 16;
      const int row  = o >> 7;
      const int colb = (o & 127) ^ ((row & 7) << 4) ^ ((row & 16) << 2);
      const char* g  = src + (size_t)(g0 + row) * Kb + (size_t)tt * 128 + colb;
      char* dst = base + i * 8192 + (tid >> 6) * 1024;  // wave-uniform base
      __builtin_amdgcn_global_load_lds(GLOBAL_AS(g), LDS_AS(dst), 16, 0, 0);
    }
  };

  f32x16 acc[4][2];
#pragma unroll
  for (int m = 0; m < 4; ++m)
#pragma unroll
    for (int n = 0; n < 2; ++n) acc[m][n] = (f32x16)0.0f;

  i32x8v aF[2][2], bF0[2], bF1[2];

  // prologue: t0 fully + t1 {Ah0, Ah1, Bh0}  (7 half-tiles = 14 loads)
  STAGE(0, 1, 0); STAGE(0, 0, 0); STAGE(0, 0, 1); STAGE(0, 1, 1);
  STAGE(1, 0, 0); STAGE(1, 0, 1); STAGE(1, 1, 0);
  VMCNT(6);   // t0 resident; t1's 3 half-tiles stay in flight
  BAR();
  LOAD_A(pA0, 0)          // A mh0 (t0)
  LOAD_B(bF0, pB0, 0)     // B nb0 (t0)

  for (int j = 0; j < NIT; ++j) {
    const int t1 = 2 * j + 1, t2 = 2 * j + 2, t3 = 2 * j + 3;
    // -- P1: stage Bh1(t1)->s1; Q(mh0,nb0); rd bF1(s0)
    STAGE(t1, 1, 1);
    SP1 MFMA_Q(0, 0, bF0) SP0
    LOAD_B(bF1, pB0, 1)
    BAR();
    // -- P2: Q(mh0,nb1); rd A mh1 (aF dead after MFMA)
    SP1 MFMA_Q(0, 1, bF1) SP0
    LOAD_A(pA0, 1)
    BAR();
    // -- P3: Q(mh1,nb1)
    SP1 MFMA_Q(1, 1, bF1) SP0
    BAR();
    // -- P4: stage Bh0(t2)+Ah0(t2)->s0; vmcnt(4) -> t1 resident; barrier;
    //        Q(mh1,nb0); rd A mh0(s1) + bF0(s1)
    STAGE(t2, 1, 0); STAGE(t2, 0, 0);
    VMCNT(4);
    BAR();
    SP1 MFMA_Q(1, 0, bF0) SP0
    LOAD_A(pA1, 0)
    LOAD_B(bF0, pB1, 0)
    BAR();
    // -- P5: stage Ah1(t2); Q(mh0,nb0)'; rd bF1(s1)
    STAGE(t2, 0, 1);
    SP1 MFMA_Q(0, 0, bF0) SP0
    LOAD_B(bF1, pB1, 1)
    BAR();
    // -- P6: stage Bh1(t2); Q(mh0,nb1)'; rd A mh1(s1)
    STAGE(t2, 1, 1);
    SP1 MFMA_Q(0, 1, bF1) SP0
    LOAD_A(pA1, 1)
    BAR();
    // -- P7: Q(mh1,nb1)'
    SP1 MFMA_Q(1, 1, bF1) SP0
    BAR();
    // -- P8: stage Ah0+Ah1+Bh0(t3)->s1; vmcnt(6) -> t2 resident; barrier;
    //        Q(mh1,nb0)'; rd A mh0(next,s0) + bF0(next,s0)
    STAGE(t3, 0, 0); STAGE(t3, 0, 1); STAGE(t3, 1, 0);
    VMCNT(6);
    BAR();
    SP1 MFMA_Q(1, 0, bF0) SP0
    LOAD_A(pA0, 0)
    LOAD_B(bF0, pB0, 0)
    BAR();
  }

  VMCNT(0);

  // epilogue: out = log(acc) + bias, nontemporal (written once, never read)
  // 32x32 C/D layout: col = lane&31, row = (reg&3) + 8*(reg>>2) + 4*(lane>>5)
  const int col0 = bcol + wc * 64 + l31;
  const int row0 = brow + wr * 128 + lk * 4;
  const float bv0 = bias[col0], bv1 = bias[col0 + 32];
#pragma unroll
  for (int mb = 0; mb < 4; ++mb) {
#pragma unroll
    for (int rg = 0; rg < 16; ++rg) {
      const int row = row0 + mb * 32 + (rg & 3) + 8 * (rg >> 2);
      const size_t ro = (size_t)row * N + col0;
      __builtin_nontemporal_store(__logf(acc[mb][0][rg]) + bv0, &out[ro]);
      __builtin_nontemporal_store(__logf(acc[mb][1][rg]) + bv1, &out[ro + 32]);
    }
  }
}

extern "C" void kernel_launch(void* const* d_in, const int* in_sizes, int n_in,
                              void* d_out, int out_size, void* d_ws, size_t ws_size,
                              hipStream_t stream) {
  const float* inputs = (const float*)d_in[0];
  const float* w      = (const float*)d_in[1];
  const float* bias   = (const float*)d_in[2];
  float* out = (float*)d_out;

  const int O = in_sizes[2];                 // 2048
  const int D = in_sizes[1] / O;             // 2048
  const size_t MD = (size_t)in_sizes[0];     // M*D
  const int M = (int)(MD / (size_t)D);       // 16384

  unsigned char* A8  = (unsigned char*)d_ws;
  unsigned char* Bt8 = (unsigned char*)d_ws + MD;

  expcvt_a8_kernel<<<2048, 256, 0, stream>>>(inputs, (unsigned*)A8, MD / 8);

  dim3 tg(O / 32, D / 32);
  expcvt_wt8_kernel<<<tg, dim3(32, 8), 0, stream>>>(w, Bt8, D, O);

  dim3 grid((M / 256) * (O / 256));
  gemm8mx_log_kernel<<<grid, 512, 0, stream>>>(A8, Bt8, bias, out, M, O, D);
}